// Round 3
// baseline (750.582 us; speedup 1.0000x reference)
//
#include <hip/hip_runtime.h>
#include <math.h>

#define N_TOK 65536
#define D_DIM 256
#define C_NUM 1024

// d_out layout (floats): out (D*N) | indices (N) | loss (1) | distances (N*C)
#define OUT_OFF   0
#define IDX_OFF   (D_DIM * N_TOK)            // 16777216
#define LOSS_OFF  (IDX_OFF + N_TOK)          // 16842752
#define DIST_OFF  (LOSS_OFF + 1)             // 16842753

#define MARGIN 0.01f
#define NPART 4096

typedef __attribute__((ext_vector_type(8))) short bf16x8;
typedef __attribute__((ext_vector_type(4))) float f32x4;

static __device__ __forceinline__ unsigned short f2bf(float f) {
  unsigned int u = __float_as_uint(f);
  unsigned int r = (u + 0x7fffu + ((u >> 16) & 1u)) >> 16;
  return (unsigned short)r;
}
static __device__ __forceinline__ float bf2f(unsigned short h) {
  return __uint_as_float(((unsigned int)h) << 16);
}

// ===========================================================================
// PATH A (ws_size >= WS_NEEDED):
//   out region (64MB, dead until k4) holds Xh (32MB) | Xl (32MB), [n][k] bf16.
//   x2 lives in IDX region (overwritten by k3's indices later).
//   ws holds: Eh | El | e2.
//   Loss partials go to PART_OFF_F inside the (dead) Xh region, exactly as
//   the proven round-1 path did.
// ISOLATION ROUND: barrier-free k2b produces distances (operand-identical to
// the proven round-1 GEMM); argmax/loss use the round-1 full-row kernels
// VERBATIM. The round-2 per-group record fusion is removed pending
// validation of the distance path.
// ===========================================================================

// ws byte offsets
#define WS_EH   0                            // u16[1024*256]   512KB
#define WS_EL   524288                       // u16[1024*256]   512KB
#define WS_E2   1048576                      // f32[1024]       4KB
#define WS_NEEDED (WS_E2 + 4096)

// Xh/Xl float offsets inside out region
#define XH_OFF_F 0
#define XL_OFF_F 8388608

// loss partials float offset (inside dead Xh region; same as round-1)
#define PART_OFF_F 263168

// ---------------------------------------------------------------------------
// kA2: bid<1024: transpose+convert X -> Xh/Xl [n][k] (64 tokens per block).
//      1024..1039: convert E -> Eh/El + e2 (in ws).
//      1040..1295: x2[n] -> IDX region (verbatim old order -> bitwise same).
// ---------------------------------------------------------------------------
__global__ __launch_bounds__(256) void kA2_prep(const float* __restrict__ X,
                                                const float* __restrict__ E,
                                                float* __restrict__ out,
                                                unsigned char* __restrict__ ws) {
  const int bid = blockIdx.x, tid = threadIdx.x;
  if (bid < 1024) {
    // X transpose+convert: thread owns token n, d-segment sg (16 d's/chunk)
    unsigned short* XhG = (unsigned short*)(out + XH_OFF_F);
    unsigned short* XlG = (unsigned short*)(out + XL_OFF_F);
    const int n = bid * 64 + (tid >> 2);
    const int sg = (tid & 3) * 16;
    unsigned short* xh = XhG + (size_t)n * D_DIM;
    unsigned short* xl = XlG + (size_t)n * D_DIM;
#pragma unroll 1
    for (int dc = 0; dc < D_DIM; dc += 64) {
      float v[16];
#pragma unroll
      for (int j = 0; j < 16; ++j) v[j] = X[(size_t)(dc + sg + j) * N_TOK + n];
      unsigned short hh[16], ll[16];
#pragma unroll
      for (int j = 0; j < 16; ++j) {
        hh[j] = f2bf(v[j]);
        ll[j] = f2bf(v[j] - bf2f(hh[j]));
      }
      *(bf16x8*)(xh + dc + sg) = *(bf16x8*)&hh[0];
      *(bf16x8*)(xh + dc + sg + 8) = *(bf16x8*)&hh[8];
      *(bf16x8*)(xl + dc + sg) = *(bf16x8*)&ll[0];
      *(bf16x8*)(xl + dc + sg + 8) = *(bf16x8*)&ll[8];
    }
  } else if (bid < 1040) {
    unsigned short* EhG = (unsigned short*)(ws + WS_EH);
    unsigned short* ElG = (unsigned short*)(ws + WS_EL);
    float* e2p = (float*)(ws + WS_E2);
    const int lane = tid & 63, w = tid >> 6;
#pragma unroll 1
    for (int cc = 0; cc < 16; ++cc) {
      const int c = (bid - 1024) * 64 + w * 16 + cc;
      const float4 v = *(const float4*)(E + (size_t)c * D_DIM + lane * 4);
      unsigned short h0 = f2bf(v.x), h1 = f2bf(v.y), h2 = f2bf(v.z), h3 = f2bf(v.w);
      unsigned short l0 = f2bf(v.x - bf2f(h0)), l1 = f2bf(v.y - bf2f(h1));
      unsigned short l2 = f2bf(v.z - bf2f(h2)), l3 = f2bf(v.w - bf2f(h3));
      ushort4 hv = make_ushort4(h0, h1, h2, h3);
      ushort4 lv = make_ushort4(l0, l1, l2, l3);
      *(ushort4*)(EhG + (size_t)c * D_DIM + lane * 4) = hv;
      *(ushort4*)(ElG + (size_t)c * D_DIM + lane * 4) = lv;
      float s = v.x * v.x + v.y * v.y + v.z * v.z + v.w * v.w;
#pragma unroll
      for (int off = 32; off; off >>= 1) s += __shfl_down(s, off, 64);
      if (lane == 0) e2p[c] = s;
    }
  } else {
    const int n = (bid - 1040) * 256 + tid;
    float s = 0.0f;
#pragma unroll 8
    for (int d = 0; d < D_DIM; ++d) {
      float v = X[(size_t)d * N_TOK + n];
      s = fmaf(v, v, s);
    }
    out[IDX_OFF + n] = s;                    // x2 scratch (k3 overwrites later)
  }
}

// ---------------------------------------------------------------------------
// k2b: barrier-free MFMA distance kernel. Block = 64 tokens x 256 codes,
// 4 waves; wave w owns 64 codes. A (Xh/Xl) and B (Eh/El) fragments loaded
// straight from global bf16 [row][k] (L2-hot, XCD-swizzled grid). No LDS,
// no barriers, no conversion. Epilogue writes distances only.
// ---------------------------------------------------------------------------
#define TM 64
#define TC 256
#define BK 32

__global__ __launch_bounds__(256) void k2b_dist(float* __restrict__ out,
                                                unsigned char* __restrict__ ws) {
  const unsigned short* __restrict__ XhG = (const unsigned short*)(out + XH_OFF_F);
  const unsigned short* __restrict__ EhG = (const unsigned short*)(ws + WS_EH);
  const float* __restrict__ e2p = (const float*)(ws + WS_E2);

  const int tid = threadIdx.x;
  const int lane = tid & 63, wave = tid >> 6;

  // XCD-swizzled decode (4 code-tiles of a token-tile land on the same XCD)
  const int bid = blockIdx.x;
  const int xcd = bid & 7;
  const int slot = bid >> 3;
  const int bx = slot & 3;
  const int by = xcd * 128 + (slot >> 2);
  const int c0 = bx * TC;
  const int n0 = by * TM;

  const int wc = c0 + wave * 64;
  const int m = lane & 15;
  const int q = lane >> 4;

  f32x4 acc[4][4];
#pragma unroll
  for (int i = 0; i < 4; ++i)
#pragma unroll
    for (int t = 0; t < 4; ++t) acc[i][t] = (f32x4){0.f, 0.f, 0.f, 0.f};

  // hoisted fragment base pointers (row*256 + q*8), offset by kb inside loop
  const unsigned short* ap[4];
  const unsigned short* bp[4];
#pragma unroll
  for (int i = 0; i < 4; ++i) ap[i] = XhG + (size_t)(n0 + i * 16 + m) * D_DIM + q * 8;
#pragma unroll
  for (int t = 0; t < 4; ++t) bp[t] = EhG + (size_t)(wc + t * 16 + m) * D_DIM + q * 8;
  const size_t loDu = (size_t)(XL_OFF_F - XH_OFF_F) * 2;  // u16 delta Xh->Xl
  const size_t loEu = (size_t)(WS_EL - WS_EH) / 2;        // u16 delta Eh->El

#pragma unroll 2
  for (int kb = 0; kb < D_DIM; kb += BK) {
    bf16x8 ah[4], al[4], bh[4], bl[4];
#pragma unroll
    for (int t = 0; t < 4; ++t) {
      bh[t] = *(const bf16x8*)(bp[t] + kb);
      bl[t] = *(const bf16x8*)(bp[t] + loEu + kb);
    }
#pragma unroll
    for (int i = 0; i < 4; ++i) {
      ah[i] = *(const bf16x8*)(ap[i] + kb);
      al[i] = *(const bf16x8*)(ap[i] + loDu + kb);
    }
#pragma unroll
    for (int i = 0; i < 4; ++i)
#pragma unroll
      for (int t = 0; t < 4; ++t) {
        acc[i][t] = __builtin_amdgcn_mfma_f32_16x16x32_bf16(ah[i], bh[t], acc[i][t], 0, 0, 0);
        acc[i][t] = __builtin_amdgcn_mfma_f32_16x16x32_bf16(ah[i], bl[t], acc[i][t], 0, 0, 0);
        acc[i][t] = __builtin_amdgcn_mfma_f32_16x16x32_bf16(al[i], bh[t], acc[i][t], 0, 0, 0);
      }
  }

  // ---- epilogue: d2 = x2 + e2 - 2*xe; dist = -sqrt(max(d2,0)) ----
  float e2v[4];
#pragma unroll
  for (int t = 0; t < 4; ++t) e2v[t] = e2p[wc + t * 16 + m];

#pragma unroll
  for (int i = 0; i < 4; ++i) {
#pragma unroll
    for (int r = 0; r < 4; ++r) {
      const int tok = n0 + i * 16 + q * 4 + r;
      const float x2v = out[IDX_OFF + tok];
      const size_t row = DIST_OFF + (size_t)tok * C_NUM;
#pragma unroll
      for (int t = 0; t < 4; ++t) {
        float d2 = fmaf(-2.0f, acc[i][t][r], x2v + e2v[t]);
        d2 = fmaxf(d2, 0.0f);
        out[row + wc + t * 16 + m] = -sqrtf(d2);
      }
    }
  }
}

// ---------------------------------------------------------------------------
// k3: round-1 VERBATIM. Wave per token (4 tokens/wave). Approx argmax from
// stored distances; candidates within MARGIN get exact fp32 d2; lex winner.
// Partials to PART_OFF_F (dead Xh region in path A; same slot as round-1).
// ---------------------------------------------------------------------------
__global__ __launch_bounds__(256) void k3_argmax(const float* __restrict__ X,
                                                 const float* __restrict__ E,
                                                 float* __restrict__ out) {
  __shared__ float lsum[4];
  const int tid = threadIdx.x, lane = tid & 63, w = tid >> 6;
  float wloss = 0.0f;

#pragma unroll 1
  for (int it = 0; it < 4; ++it) {
    const int n = blockIdx.x * 16 + w * 4 + it;
    const float* row = out + DIST_OFF + (size_t)n * C_NUM;

    float v[16];
    float best = -3.4e38f;
    int bi = 0x7fffffff;
#pragma unroll
    for (int j = 0; j < 16; ++j) {
      v[j] = row[j * 64 + lane];
      if (v[j] > best) { best = v[j]; bi = j * 64 + lane; }
    }
#pragma unroll
    for (int off = 32; off; off >>= 1) {
      const float ov = __shfl_xor(best, off, 64);
      const int oi = __shfl_xor(bi, off, 64);
      if (ov > best || (ov == best && oi < bi)) { best = ov; bi = oi; }
    }
    const float thr = best - MARGIN;
    unsigned long long masks[16];
    int total = 0;
#pragma unroll
    for (int j = 0; j < 16; ++j) {
      masks[j] = __ballot(v[j] > thr);
      total += __popcll(masks[j]);
    }
    float best_d2 = best * best;
    int best_idx = bi;
    if (total > 1) {
      best_d2 = 3.4e38f;
      best_idx = 0x7fffffff;
      for (int j = 0; j < 16; ++j) {
        unsigned long long mm = masks[j];
        while (mm) {
          const int l = __ffsll((long long)mm) - 1;
          mm &= mm - 1;
          const int c = j * 64 + l;
          float sx = 0.f, se = 0.f, sxe = 0.f;
#pragma unroll
          for (int r = 0; r < 4; ++r) {
            const int d = r * 64 + lane;
            const float xv = X[(size_t)d * N_TOK + n];
            const float ev = E[(size_t)c * D_DIM + d];
            sx = fmaf(xv, xv, sx);
            se = fmaf(ev, ev, se);
            sxe = fmaf(xv, ev, sxe);
          }
          float d2 = fmaf(-2.f, sxe, sx + se);
#pragma unroll
          for (int off = 32; off; off >>= 1) d2 += __shfl_xor(d2, off, 64);
          d2 = fmaxf(d2, 0.f);
          if (d2 < best_d2 || (d2 == best_d2 && c < best_idx)) {
            best_d2 = d2; best_idx = c;
          }
        }
      }
    }
    if (lane == 0) out[IDX_OFF + n] = (float)best_idx;
    wloss += best_d2;
  }
  if (lane == 0) lsum[w] = wloss;
  __syncthreads();
  if (tid == 0)
    out[PART_OFF_F + blockIdx.x] = lsum[0] + lsum[1] + lsum[2] + lsum[3];
}

// ---------------------------------------------------------------------------
// k3b: round-1 VERBATIM. Reduce 4096 partials -> loss.
// ---------------------------------------------------------------------------
__global__ __launch_bounds__(256) void k3b_loss(float* __restrict__ out) {
  __shared__ float red[4];
  const int tid = threadIdx.x, lane = tid & 63, w = tid >> 6;
  float s = 0.0f;
#pragma unroll
  for (int i = 0; i < NPART / 256; ++i) s += out[PART_OFF_F + i * 256 + tid];
#pragma unroll
  for (int off = 32; off; off >>= 1) s += __shfl_down(s, off, 64);
  if (lane == 0) red[w] = s;
  __syncthreads();
  if (tid == 0)
    out[LOSS_OFF] = (red[0] + red[1] + red[2] + red[3]) *
                    (0.25f / ((float)N_TOK * (float)D_DIM));
}

// ===========================================================================
// PATH B (fallback, ws unusable): round-1 kernels verbatim.
// ===========================================================================
#define EH_OFF_F  0
#define EL_OFF_F  131072
#define E2_OFF_F  262144

__global__ __launch_bounds__(256) void kA_prep(const float* __restrict__ X,
                                               const float* __restrict__ E,
                                               float* __restrict__ out) {
  const int bid = blockIdx.x, tid = threadIdx.x;
  if (bid < 256) {
    const int n = bid * 256 + tid;
    float s = 0.0f;
#pragma unroll 8
    for (int d = 0; d < D_DIM; ++d) {
      float v = X[(size_t)d * N_TOK + n];
      s = fmaf(v, v, s);
    }
    out[IDX_OFF + n] = s;
  } else {
    unsigned short* EhG = (unsigned short*)(out + EH_OFF_F);
    unsigned short* ElG = (unsigned short*)(out + EL_OFF_F);
    const int lane = tid & 63, w = tid >> 6;
#pragma unroll 1
    for (int cc = 0; cc < 16; ++cc) {
      const int c = (bid - 256) * 64 + w * 16 + cc;
      const float4 v = *(const float4*)(E + (size_t)c * D_DIM + lane * 4);
      unsigned short h0 = f2bf(v.x), h1 = f2bf(v.y), h2 = f2bf(v.z), h3 = f2bf(v.w);
      unsigned short l0 = f2bf(v.x - bf2f(h0)), l1 = f2bf(v.y - bf2f(h1));
      unsigned short l2 = f2bf(v.z - bf2f(h2)), l3 = f2bf(v.w - bf2f(h3));
      ushort4 hv = make_ushort4(h0, h1, h2, h3);
      ushort4 lv = make_ushort4(l0, l1, l2, l3);
      *(ushort4*)(EhG + (size_t)c * D_DIM + lane * 4) = hv;
      *(ushort4*)(ElG + (size_t)c * D_DIM + lane * 4) = lv;
      float s = v.x * v.x + v.y * v.y + v.z * v.z + v.w * v.w;
#pragma unroll
      for (int off = 32; off; off >>= 1) s += __shfl_down(s, off, 64);
      if (lane == 0) out[E2_OFF_F + c] = s;
    }
  }
}

#define XS 40

__global__ __launch_bounds__(256) void k2_dist(const float* __restrict__ X,
                                               float* __restrict__ out) {
  __shared__ __align__(16) unsigned short xh[2][TM * XS];
  __shared__ __align__(16) unsigned short xl[2][TM * XS];

  const unsigned short* __restrict__ EhG = (const unsigned short*)(out + EH_OFF_F);
  const unsigned short* __restrict__ ElG = (const unsigned short*)(out + EL_OFF_F);

  const int tid = threadIdx.x;
  const int lane = tid & 63, wave = tid >> 6;
  const int bid = blockIdx.x;
  const int xcd = bid & 7;
  const int slot = bid >> 3;
  const int bx = slot & 3;
  const int by = xcd * 128 + (slot >> 2);
  const int c0 = bx * TC;
  const int n0 = by * TM;

  const int wc = c0 + wave * 64;
  const int m = lane & 15;
  const int q = lane >> 4;

  f32x4 acc[4][4];
#pragma unroll
  for (int i = 0; i < 4; ++i)
#pragma unroll
    for (int t = 0; t < 4; ++t) acc[i][t] = (f32x4){0.f, 0.f, 0.f, 0.f};

  const int sn = lane;
  const int kg = wave;

  float xv[8];
  {
    const float* xp = X + (size_t)(kg * 8) * N_TOK + n0 + sn;
#pragma unroll
    for (int j = 0; j < 8; ++j) xv[j] = xp[(size_t)j * N_TOK];
  }

#pragma unroll 1
  for (int kb = 0; kb < D_DIM; kb += BK) {
    const int p = (kb >> 5) & 1;
    bf16x8 bh[4], bl[4];
#pragma unroll
    for (int t = 0; t < 4; ++t) {
      const size_t eoff = (size_t)(wc + t * 16 + m) * D_DIM + kb + q * 8;
      bh[t] = *(const bf16x8*)(EhG + eoff);
      bl[t] = *(const bf16x8*)(ElG + eoff);
    }
    unsigned short hh[8], ll[8];
#pragma unroll
    for (int j = 0; j < 8; ++j) {
      hh[j] = f2bf(xv[j]);
      ll[j] = f2bf(xv[j] - bf2f(hh[j]));
    }
    *(bf16x8*)&xh[p][sn * XS + kg * 8] = *(bf16x8*)hh;
    *(bf16x8*)&xl[p][sn * XS + kg * 8] = *(bf16x8*)ll;
    if (kb + BK < D_DIM) {
      const float* xp = X + (size_t)(kb + BK + kg * 8) * N_TOK + n0 + sn;
#pragma unroll
      for (int j = 0; j < 8; ++j) xv[j] = xp[(size_t)j * N_TOK];
    }
    __syncthreads();
    bf16x8 ah[4], al[4];
#pragma unroll
    for (int i = 0; i < 4; ++i) {
      const int ro = (i * 16 + m) * XS + q * 8;
      ah[i] = *(const bf16x8*)&xh[p][ro];
      al[i] = *(const bf16x8*)&xl[p][ro];
    }
#pragma unroll
    for (int i = 0; i < 4; ++i)
#pragma unroll
      for (int t = 0; t < 4; ++t) {
        acc[i][t] = __builtin_amdgcn_mfma_f32_16x16x32_bf16(ah[i], bh[t], acc[i][t], 0, 0, 0);
        acc[i][t] = __builtin_amdgcn_mfma_f32_16x16x32_bf16(ah[i], bl[t], acc[i][t], 0, 0, 0);
        acc[i][t] = __builtin_amdgcn_mfma_f32_16x16x32_bf16(al[i], bh[t], acc[i][t], 0, 0, 0);
      }
  }

  float e2v[4];
#pragma unroll
  for (int t = 0; t < 4; ++t) e2v[t] = out[E2_OFF_F + wc + t * 16 + m];

#pragma unroll
  for (int i = 0; i < 4; ++i) {
#pragma unroll
    for (int r = 0; r < 4; ++r) {
      const int tok = n0 + i * 16 + q * 4 + r;
      const float x2v = out[IDX_OFF + tok];
      const size_t row = DIST_OFF + (size_t)tok * C_NUM;
#pragma unroll
      for (int t = 0; t < 4; ++t) {
        float d2 = fmaf(-2.0f, acc[i][t][r], x2v + e2v[t]);
        d2 = fmaxf(d2, 0.0f);
        out[row + wc + t * 16 + m] = -sqrtf(d2);
      }
    }
  }
}

// ---------------------------------------------------------------------------
// k4: shared by both paths. out[d][n] = E[idx[n]][d].
// ---------------------------------------------------------------------------
__global__ __launch_bounds__(256) void k4_gather(const float* __restrict__ E,
                                                 float* __restrict__ out) {
  const int g = blockIdx.x * 256 + threadIdx.x;
  const int n = g * 4;
  const int i0 = (int)out[IDX_OFF + n + 0];
  const int i1 = (int)out[IDX_OFF + n + 1];
  const int i2 = (int)out[IDX_OFF + n + 2];
  const int i3 = (int)out[IDX_OFF + n + 3];
  const float* e0 = E + (size_t)i0 * D_DIM;
  const float* e1 = E + (size_t)i1 * D_DIM;
  const float* e2 = E + (size_t)i2 * D_DIM;
  const float* e3 = E + (size_t)i3 * D_DIM;
  const int d0 = blockIdx.y * 32;
#pragma unroll 4
  for (int d = d0; d < d0 + 32; ++d) {
    float4 wv = make_float4(e0[d], e1[d], e2[d], e3[d]);
    *(float4*)&out[(size_t)d * N_TOK + n] = wv;
  }
}

extern "C" void kernel_launch(void* const* d_in, const int* in_sizes, int n_in,
                              void* d_out, int out_size, void* d_ws, size_t ws_size,
                              hipStream_t stream) {
  const float* X = (const float*)d_in[0];   // (1, 256, 65536)
  const float* E = (const float*)d_in[1];   // (1, 1024, 256)
  float* out = (float*)d_out;

  if (ws_size >= WS_NEEDED && d_ws != nullptr) {
    unsigned char* ws = (unsigned char*)d_ws;
    hipLaunchKernelGGL(kA2_prep, dim3(1296), dim3(256), 0, stream, X, E, out, ws);
    hipLaunchKernelGGL(k2b_dist, dim3((C_NUM / TC) * (N_TOK / TM)), dim3(256), 0,
                       stream, out, ws);
    hipLaunchKernelGGL(k3_argmax, dim3(N_TOK / 16), dim3(256), 0, stream, X, E, out);
    hipLaunchKernelGGL(k3b_loss, dim3(1), dim3(256), 0, stream, out);
    hipLaunchKernelGGL(k4_gather, dim3(N_TOK / 4 / 256, 8), dim3(256), 0, stream,
                       E, out);
  } else {
    hipLaunchKernelGGL(kA_prep, dim3(272), dim3(256), 0, stream, X, E, out);
    hipLaunchKernelGGL(k2_dist, dim3((C_NUM / TC) * (N_TOK / TM)), dim3(256), 0,
                       stream, X, out);
    hipLaunchKernelGGL(k3_argmax, dim3(N_TOK / 16), dim3(256), 0, stream, X, E, out);
    hipLaunchKernelGGL(k3b_loss, dim3(1), dim3(256), 0, stream, out);
    hipLaunchKernelGGL(k4_gather, dim3(N_TOK / 4 / 256, 8), dim3(256), 0, stream,
                       E, out);
  }
}

// Round 4
// 656.932 us; speedup vs baseline: 1.1426x; 1.1426x over previous
//
#include <hip/hip_runtime.h>
#include <math.h>

#define N_TOK 65536
#define D_DIM 256
#define C_NUM 1024

// d_out layout (floats): out (D*N) | indices (N) | loss (1) | distances (N*C)
#define OUT_OFF   0
#define IDX_OFF   (D_DIM * N_TOK)            // 16777216
#define LOSS_OFF  (IDX_OFF + N_TOK)          // 16842752
#define DIST_OFF  (LOSS_OFF + 1)             // 16842753

#define MARGIN 0.01f
#define NPART 4096

typedef __attribute__((ext_vector_type(8))) short bf16x8;
typedef __attribute__((ext_vector_type(4))) float f32x4;

static __device__ __forceinline__ unsigned short f2bf(float f) {
  unsigned int u = __float_as_uint(f);
  unsigned int r = (u + 0x7fffu + ((u >> 16) & 1u)) >> 16;
  return (unsigned short)r;
}
static __device__ __forceinline__ float bf2f(unsigned short h) {
  return __uint_as_float(((unsigned int)h) << 16);
}

// ===========================================================================
// PATH A (ws_size >= WS_NEEDED):
//   out region (64MB, dead until k4) holds Xh (32MB) | Xl (32MB), [n][k] bf16.
//   x2 lives in IDX region (overwritten by k3's indices later).
//   ws holds: Eh | El | e2. Loss partials at PART_OFF_F (dead Xh region).
// k2c: stage the whole 64-token A-tile (Xh+Xl, 64KB) into padded LDS ONCE
// (one barrier in the entire kernel), then 8 barrier-free K-chunks of
// {8 LDS b128 (A) + 8 global b128 (B, L2-hot) + 48 MFMA}. No in-loop
// conversion (kA2 preconverted). Operand-identical to the validated round-3
// distance path -> bitwise-identical distances.
// ===========================================================================

// ws byte offsets
#define WS_EH   0                            // u16[1024*256]   512KB
#define WS_EL   524288                       // u16[1024*256]   512KB
#define WS_E2   1048576                      // f32[1024]       4KB
#define WS_NEEDED (WS_E2 + 4096)

// Xh/Xl float offsets inside out region
#define XH_OFF_F 0
#define XL_OFF_F 8388608

// loss partials float offset (inside dead Xh region; same as round-1)
#define PART_OFF_F 263168

// ---------------------------------------------------------------------------
// kA2: bid<1024: transpose+convert X -> Xh/Xl [n][k] (64 tokens per block).
//      1024..1039: convert E -> Eh/El + e2 (in ws).
//      1040..1295: x2[n] -> IDX region (verbatim old order -> bitwise same).
// ---------------------------------------------------------------------------
__global__ __launch_bounds__(256) void kA2_prep(const float* __restrict__ X,
                                                const float* __restrict__ E,
                                                float* __restrict__ out,
                                                unsigned char* __restrict__ ws) {
  const int bid = blockIdx.x, tid = threadIdx.x;
  if (bid < 1024) {
    // X transpose+convert: thread owns token n, d-segment sg (16 d's/chunk)
    unsigned short* XhG = (unsigned short*)(out + XH_OFF_F);
    unsigned short* XlG = (unsigned short*)(out + XL_OFF_F);
    const int n = bid * 64 + (tid >> 2);
    const int sg = (tid & 3) * 16;
    unsigned short* xh = XhG + (size_t)n * D_DIM;
    unsigned short* xl = XlG + (size_t)n * D_DIM;
#pragma unroll 1
    for (int dc = 0; dc < D_DIM; dc += 64) {
      float v[16];
#pragma unroll
      for (int j = 0; j < 16; ++j) v[j] = X[(size_t)(dc + sg + j) * N_TOK + n];
      unsigned short hh[16], ll[16];
#pragma unroll
      for (int j = 0; j < 16; ++j) {
        hh[j] = f2bf(v[j]);
        ll[j] = f2bf(v[j] - bf2f(hh[j]));
      }
      *(bf16x8*)(xh + dc + sg) = *(bf16x8*)&hh[0];
      *(bf16x8*)(xh + dc + sg + 8) = *(bf16x8*)&hh[8];
      *(bf16x8*)(xl + dc + sg) = *(bf16x8*)&ll[0];
      *(bf16x8*)(xl + dc + sg + 8) = *(bf16x8*)&ll[8];
    }
  } else if (bid < 1040) {
    unsigned short* EhG = (unsigned short*)(ws + WS_EH);
    unsigned short* ElG = (unsigned short*)(ws + WS_EL);
    float* e2p = (float*)(ws + WS_E2);
    const int lane = tid & 63, w = tid >> 6;
#pragma unroll 1
    for (int cc = 0; cc < 16; ++cc) {
      const int c = (bid - 1024) * 64 + w * 16 + cc;
      const float4 v = *(const float4*)(E + (size_t)c * D_DIM + lane * 4);
      unsigned short h0 = f2bf(v.x), h1 = f2bf(v.y), h2 = f2bf(v.z), h3 = f2bf(v.w);
      unsigned short l0 = f2bf(v.x - bf2f(h0)), l1 = f2bf(v.y - bf2f(h1));
      unsigned short l2 = f2bf(v.z - bf2f(h2)), l3 = f2bf(v.w - bf2f(h3));
      ushort4 hv = make_ushort4(h0, h1, h2, h3);
      ushort4 lv = make_ushort4(l0, l1, l2, l3);
      *(ushort4*)(EhG + (size_t)c * D_DIM + lane * 4) = hv;
      *(ushort4*)(ElG + (size_t)c * D_DIM + lane * 4) = lv;
      float s = v.x * v.x + v.y * v.y + v.z * v.z + v.w * v.w;
#pragma unroll
      for (int off = 32; off; off >>= 1) s += __shfl_down(s, off, 64);
      if (lane == 0) e2p[c] = s;
    }
  } else {
    const int n = (bid - 1040) * 256 + tid;
    float s = 0.0f;
#pragma unroll 8
    for (int d = 0; d < D_DIM; ++d) {
      float v = X[(size_t)d * N_TOK + n];
      s = fmaf(v, v, s);
    }
    out[IDX_OFF + n] = s;                    // x2 scratch (k3 overwrites later)
  }
}

// ---------------------------------------------------------------------------
// k2c: stage-once LDS A-tile + barrier-free MFMA loop.
// Block = 64 tokens x 256 codes, 4 waves; wave w owns 64 codes.
// LDS: xh/xl [64][XS2] u16, XS2 = 264 (256+8 pad -> 528B row stride,
// bank-start 4*(row+q) mod 32: 8 lanes per 16B slot = round-1's benign
// conflict profile). One __syncthreads() total.
// ---------------------------------------------------------------------------
#define TM 64
#define TC 256
#define BK 32
#define XS2 264   // u16 row stride (256 + 8 pad); 528B, 16B-aligned

__global__ __launch_bounds__(256) void k2c_dist(float* __restrict__ out,
                                                unsigned char* __restrict__ ws) {
  __shared__ __align__(16) unsigned short xh[TM * XS2];
  __shared__ __align__(16) unsigned short xl[TM * XS2];

  const unsigned short* __restrict__ XhG = (const unsigned short*)(out + XH_OFF_F);
  const unsigned short* __restrict__ XlG = (const unsigned short*)(out + XL_OFF_F);
  const unsigned short* __restrict__ EhG = (const unsigned short*)(ws + WS_EH);
  const float* __restrict__ e2p = (const float*)(ws + WS_E2);

  const int tid = threadIdx.x;
  const int lane = tid & 63, wave = tid >> 6;

  // XCD-swizzled decode (4 code-tiles of a token-tile land on the same XCD)
  const int bid = blockIdx.x;
  const int xcd = bid & 7;
  const int slot = bid >> 3;
  const int bx = slot & 3;
  const int by = xcd * 128 + (slot >> 2);
  const int c0 = bx * TC;
  const int n0 = by * TM;

  const int wc = c0 + wave * 64;
  const int m = lane & 15;
  const int q = lane >> 4;

  // ---- stage whole A-tile once: thread owns token tl, 64-u16 segment ----
  {
    const int tl = tid >> 2;
    const int seg = (tid & 3) * 64;
    const unsigned short* gh = XhG + (size_t)(n0 + tl) * D_DIM + seg;
    const unsigned short* gl = XlG + (size_t)(n0 + tl) * D_DIM + seg;
    unsigned short* sh = xh + tl * XS2 + seg;
    unsigned short* sl = xl + tl * XS2 + seg;
#pragma unroll
    for (int j = 0; j < 8; ++j) {
      *(bf16x8*)(sh + j * 8) = *(const bf16x8*)(gh + j * 8);
      *(bf16x8*)(sl + j * 8) = *(const bf16x8*)(gl + j * 8);
    }
  }
  __syncthreads();   // the only barrier in this kernel

  f32x4 acc[4][4];
#pragma unroll
  for (int i = 0; i < 4; ++i)
#pragma unroll
    for (int t = 0; t < 4; ++t) acc[i][t] = (f32x4){0.f, 0.f, 0.f, 0.f};

  // hoisted B fragment base pointers (row*256 + q*8), offset by kb in loop
  const unsigned short* bp[4];
#pragma unroll
  for (int t = 0; t < 4; ++t) bp[t] = EhG + (size_t)(wc + t * 16 + m) * D_DIM + q * 8;
  const size_t loEu = (size_t)(WS_EL - WS_EH) / 2;        // u16 delta Eh->El

#pragma unroll 2
  for (int kb = 0; kb < D_DIM; kb += BK) {
    bf16x8 ah[4], al[4], bh[4], bl[4];
#pragma unroll
    for (int t = 0; t < 4; ++t) {
      bh[t] = *(const bf16x8*)(bp[t] + kb);
      bl[t] = *(const bf16x8*)(bp[t] + loEu + kb);
    }
#pragma unroll
    for (int i = 0; i < 4; ++i) {
      const int ro = (i * 16 + m) * XS2 + kb + q * 8;
      ah[i] = *(const bf16x8*)&xh[ro];
      al[i] = *(const bf16x8*)&xl[ro];
    }
#pragma unroll
    for (int i = 0; i < 4; ++i)
#pragma unroll
      for (int t = 0; t < 4; ++t) {
        acc[i][t] = __builtin_amdgcn_mfma_f32_16x16x32_bf16(ah[i], bh[t], acc[i][t], 0, 0, 0);
        acc[i][t] = __builtin_amdgcn_mfma_f32_16x16x32_bf16(ah[i], bl[t], acc[i][t], 0, 0, 0);
        acc[i][t] = __builtin_amdgcn_mfma_f32_16x16x32_bf16(al[i], bh[t], acc[i][t], 0, 0, 0);
      }
  }

  // ---- epilogue: d2 = x2 + e2 - 2*xe; dist = -sqrt(max(d2,0)) ----
  float e2v[4];
#pragma unroll
  for (int t = 0; t < 4; ++t) e2v[t] = e2p[wc + t * 16 + m];

#pragma unroll
  for (int i = 0; i < 4; ++i) {
#pragma unroll
    for (int r = 0; r < 4; ++r) {
      const int tok = n0 + i * 16 + q * 4 + r;
      const float x2v = out[IDX_OFF + tok];
      const size_t row = DIST_OFF + (size_t)tok * C_NUM;
#pragma unroll
      for (int t = 0; t < 4; ++t) {
        float d2 = fmaf(-2.0f, acc[i][t][r], x2v + e2v[t]);
        d2 = fmaxf(d2, 0.0f);
        out[row + wc + t * 16 + m] = -sqrtf(d2);
      }
    }
  }
}

// ---------------------------------------------------------------------------
// k3: round-1 VERBATIM. Wave per token (4 tokens/wave). Approx argmax from
// stored distances; candidates within MARGIN get exact fp32 d2; lex winner.
// ---------------------------------------------------------------------------
__global__ __launch_bounds__(256) void k3_argmax(const float* __restrict__ X,
                                                 const float* __restrict__ E,
                                                 float* __restrict__ out) {
  __shared__ float lsum[4];
  const int tid = threadIdx.x, lane = tid & 63, w = tid >> 6;
  float wloss = 0.0f;

#pragma unroll 1
  for (int it = 0; it < 4; ++it) {
    const int n = blockIdx.x * 16 + w * 4 + it;
    const float* row = out + DIST_OFF + (size_t)n * C_NUM;

    float v[16];
    float best = -3.4e38f;
    int bi = 0x7fffffff;
#pragma unroll
    for (int j = 0; j < 16; ++j) {
      v[j] = row[j * 64 + lane];
      if (v[j] > best) { best = v[j]; bi = j * 64 + lane; }
    }
#pragma unroll
    for (int off = 32; off; off >>= 1) {
      const float ov = __shfl_xor(best, off, 64);
      const int oi = __shfl_xor(bi, off, 64);
      if (ov > best || (ov == best && oi < bi)) { best = ov; bi = oi; }
    }
    const float thr = best - MARGIN;
    unsigned long long masks[16];
    int total = 0;
#pragma unroll
    for (int j = 0; j < 16; ++j) {
      masks[j] = __ballot(v[j] > thr);
      total += __popcll(masks[j]);
    }
    float best_d2 = best * best;
    int best_idx = bi;
    if (total > 1) {
      best_d2 = 3.4e38f;
      best_idx = 0x7fffffff;
      for (int j = 0; j < 16; ++j) {
        unsigned long long mm = masks[j];
        while (mm) {
          const int l = __ffsll((long long)mm) - 1;
          mm &= mm - 1;
          const int c = j * 64 + l;
          float sx = 0.f, se = 0.f, sxe = 0.f;
#pragma unroll
          for (int r = 0; r < 4; ++r) {
            const int d = r * 64 + lane;
            const float xv = X[(size_t)d * N_TOK + n];
            const float ev = E[(size_t)c * D_DIM + d];
            sx = fmaf(xv, xv, sx);
            se = fmaf(ev, ev, se);
            sxe = fmaf(xv, ev, sxe);
          }
          float d2 = fmaf(-2.f, sxe, sx + se);
#pragma unroll
          for (int off = 32; off; off >>= 1) d2 += __shfl_xor(d2, off, 64);
          d2 = fmaxf(d2, 0.f);
          if (d2 < best_d2 || (d2 == best_d2 && c < best_idx)) {
            best_d2 = d2; best_idx = c;
          }
        }
      }
    }
    if (lane == 0) out[IDX_OFF + n] = (float)best_idx;
    wloss += best_d2;
  }
  if (lane == 0) lsum[w] = wloss;
  __syncthreads();
  if (tid == 0)
    out[PART_OFF_F + blockIdx.x] = lsum[0] + lsum[1] + lsum[2] + lsum[3];
}

// ---------------------------------------------------------------------------
// k3b: round-1 VERBATIM. Reduce 4096 partials -> loss.
// ---------------------------------------------------------------------------
__global__ __launch_bounds__(256) void k3b_loss(float* __restrict__ out) {
  __shared__ float red[4];
  const int tid = threadIdx.x, lane = tid & 63, w = tid >> 6;
  float s = 0.0f;
#pragma unroll
  for (int i = 0; i < NPART / 256; ++i) s += out[PART_OFF_F + i * 256 + tid];
#pragma unroll
  for (int off = 32; off; off >>= 1) s += __shfl_down(s, off, 64);
  if (lane == 0) red[w] = s;
  __syncthreads();
  if (tid == 0)
    out[LOSS_OFF] = (red[0] + red[1] + red[2] + red[3]) *
                    (0.25f / ((float)N_TOK * (float)D_DIM));
}

// ===========================================================================
// PATH B (fallback, ws unusable): round-1 kernels verbatim.
// ===========================================================================
#define EH_OFF_F  0
#define EL_OFF_F  131072
#define E2_OFF_F  262144

__global__ __launch_bounds__(256) void kA_prep(const float* __restrict__ X,
                                               const float* __restrict__ E,
                                               float* __restrict__ out) {
  const int bid = blockIdx.x, tid = threadIdx.x;
  if (bid < 256) {
    const int n = bid * 256 + tid;
    float s = 0.0f;
#pragma unroll 8
    for (int d = 0; d < D_DIM; ++d) {
      float v = X[(size_t)d * N_TOK + n];
      s = fmaf(v, v, s);
    }
    out[IDX_OFF + n] = s;
  } else {
    unsigned short* EhG = (unsigned short*)(out + EH_OFF_F);
    unsigned short* ElG = (unsigned short*)(out + EL_OFF_F);
    const int lane = tid & 63, w = tid >> 6;
#pragma unroll 1
    for (int cc = 0; cc < 16; ++cc) {
      const int c = (bid - 256) * 64 + w * 16 + cc;
      const float4 v = *(const float4*)(E + (size_t)c * D_DIM + lane * 4);
      unsigned short h0 = f2bf(v.x), h1 = f2bf(v.y), h2 = f2bf(v.z), h3 = f2bf(v.w);
      unsigned short l0 = f2bf(v.x - bf2f(h0)), l1 = f2bf(v.y - bf2f(h1));
      unsigned short l2 = f2bf(v.z - bf2f(h2)), l3 = f2bf(v.w - bf2f(h3));
      ushort4 hv = make_ushort4(h0, h1, h2, h3);
      ushort4 lv = make_ushort4(l0, l1, l2, l3);
      *(ushort4*)(EhG + (size_t)c * D_DIM + lane * 4) = hv;
      *(ushort4*)(ElG + (size_t)c * D_DIM + lane * 4) = lv;
      float s = v.x * v.x + v.y * v.y + v.z * v.z + v.w * v.w;
#pragma unroll
      for (int off = 32; off; off >>= 1) s += __shfl_down(s, off, 64);
      if (lane == 0) out[E2_OFF_F + c] = s;
    }
  }
}

#define XS 40

__global__ __launch_bounds__(256) void k2_dist(const float* __restrict__ X,
                                               float* __restrict__ out) {
  __shared__ __align__(16) unsigned short xhb[2][TM * XS];
  __shared__ __align__(16) unsigned short xlb[2][TM * XS];

  const unsigned short* __restrict__ EhG = (const unsigned short*)(out + EH_OFF_F);
  const unsigned short* __restrict__ ElG = (const unsigned short*)(out + EL_OFF_F);

  const int tid = threadIdx.x;
  const int lane = tid & 63, wave = tid >> 6;
  const int bid = blockIdx.x;
  const int xcd = bid & 7;
  const int slot = bid >> 3;
  const int bx = slot & 3;
  const int by = xcd * 128 + (slot >> 2);
  const int c0 = bx * TC;
  const int n0 = by * TM;

  const int wc = c0 + wave * 64;
  const int m = lane & 15;
  const int q = lane >> 4;

  f32x4 acc[4][4];
#pragma unroll
  for (int i = 0; i < 4; ++i)
#pragma unroll
    for (int t = 0; t < 4; ++t) acc[i][t] = (f32x4){0.f, 0.f, 0.f, 0.f};

  const int sn = lane;
  const int kg = wave;

  float xv[8];
  {
    const float* xp = X + (size_t)(kg * 8) * N_TOK + n0 + sn;
#pragma unroll
    for (int j = 0; j < 8; ++j) xv[j] = xp[(size_t)j * N_TOK];
  }

#pragma unroll 1
  for (int kb = 0; kb < D_DIM; kb += BK) {
    const int p = (kb >> 5) & 1;
    bf16x8 bh[4], bl[4];
#pragma unroll
    for (int t = 0; t < 4; ++t) {
      const size_t eoff = (size_t)(wc + t * 16 + m) * D_DIM + kb + q * 8;
      bh[t] = *(const bf16x8*)(EhG + eoff);
      bl[t] = *(const bf16x8*)(ElG + eoff);
    }
    unsigned short hh[8], ll[8];
#pragma unroll
    for (int j = 0; j < 8; ++j) {
      hh[j] = f2bf(xv[j]);
      ll[j] = f2bf(xv[j] - bf2f(hh[j]));
    }
    *(bf16x8*)&xhb[p][sn * XS + kg * 8] = *(bf16x8*)hh;
    *(bf16x8*)&xlb[p][sn * XS + kg * 8] = *(bf16x8*)ll;
    if (kb + BK < D_DIM) {
      const float* xp = X + (size_t)(kb + BK + kg * 8) * N_TOK + n0 + sn;
#pragma unroll
      for (int j = 0; j < 8; ++j) xv[j] = xp[(size_t)j * N_TOK];
    }
    __syncthreads();
    bf16x8 ah[4], al[4];
#pragma unroll
    for (int i = 0; i < 4; ++i) {
      const int ro = (i * 16 + m) * XS + q * 8;
      ah[i] = *(const bf16x8*)&xhb[p][ro];
      al[i] = *(const bf16x8*)&xlb[p][ro];
    }
#pragma unroll
    for (int i = 0; i < 4; ++i)
#pragma unroll
      for (int t = 0; t < 4; ++t) {
        acc[i][t] = __builtin_amdgcn_mfma_f32_16x16x32_bf16(ah[i], bh[t], acc[i][t], 0, 0, 0);
        acc[i][t] = __builtin_amdgcn_mfma_f32_16x16x32_bf16(ah[i], bl[t], acc[i][t], 0, 0, 0);
        acc[i][t] = __builtin_amdgcn_mfma_f32_16x16x32_bf16(al[i], bh[t], acc[i][t], 0, 0, 0);
      }
  }

  float e2v[4];
#pragma unroll
  for (int t = 0; t < 4; ++t) e2v[t] = out[E2_OFF_F + wc + t * 16 + m];

#pragma unroll
  for (int i = 0; i < 4; ++i) {
#pragma unroll
    for (int r = 0; r < 4; ++r) {
      const int tok = n0 + i * 16 + q * 4 + r;
      const float x2v = out[IDX_OFF + tok];
      const size_t row = DIST_OFF + (size_t)tok * C_NUM;
#pragma unroll
      for (int t = 0; t < 4; ++t) {
        float d2 = fmaf(-2.0f, acc[i][t][r], x2v + e2v[t]);
        d2 = fmaxf(d2, 0.0f);
        out[row + wc + t * 16 + m] = -sqrtf(d2);
      }
    }
  }
}

// ---------------------------------------------------------------------------
// k4: shared by both paths. out[d][n] = E[idx[n]][d].
// ---------------------------------------------------------------------------
__global__ __launch_bounds__(256) void k4_gather(const float* __restrict__ E,
                                                 float* __restrict__ out) {
  const int g = blockIdx.x * 256 + threadIdx.x;
  const int n = g * 4;
  const int i0 = (int)out[IDX_OFF + n + 0];
  const int i1 = (int)out[IDX_OFF + n + 1];
  const int i2 = (int)out[IDX_OFF + n + 2];
  const int i3 = (int)out[IDX_OFF + n + 3];
  const float* e0 = E + (size_t)i0 * D_DIM;
  const float* e1 = E + (size_t)i1 * D_DIM;
  const float* e2 = E + (size_t)i2 * D_DIM;
  const float* e3 = E + (size_t)i3 * D_DIM;
  const int d0 = blockIdx.y * 32;
#pragma unroll 4
  for (int d = d0; d < d0 + 32; ++d) {
    float4 wv = make_float4(e0[d], e1[d], e2[d], e3[d]);
    *(float4*)&out[(size_t)d * N_TOK + n] = wv;
  }
}

extern "C" void kernel_launch(void* const* d_in, const int* in_sizes, int n_in,
                              void* d_out, int out_size, void* d_ws, size_t ws_size,
                              hipStream_t stream) {
  const float* X = (const float*)d_in[0];   // (1, 256, 65536)
  const float* E = (const float*)d_in[1];   // (1, 1024, 256)
  float* out = (float*)d_out;

  if (ws_size >= WS_NEEDED && d_ws != nullptr) {
    unsigned char* ws = (unsigned char*)d_ws;
    hipLaunchKernelGGL(kA2_prep, dim3(1296), dim3(256), 0, stream, X, E, out, ws);
    hipLaunchKernelGGL(k2c_dist, dim3((C_NUM / TC) * (N_TOK / TM)), dim3(256), 0,
                       stream, out, ws);
    hipLaunchKernelGGL(k3_argmax, dim3(N_TOK / 16), dim3(256), 0, stream, X, E, out);
    hipLaunchKernelGGL(k3b_loss, dim3(1), dim3(256), 0, stream, out);
    hipLaunchKernelGGL(k4_gather, dim3(N_TOK / 4 / 256, 8), dim3(256), 0, stream,
                       E, out);
  } else {
    hipLaunchKernelGGL(kA_prep, dim3(272), dim3(256), 0, stream, X, E, out);
    hipLaunchKernelGGL(k2_dist, dim3((C_NUM / TC) * (N_TOK / TM)), dim3(256), 0,
                       stream, X, out);
    hipLaunchKernelGGL(k3_argmax, dim3(N_TOK / 16), dim3(256), 0, stream, X, E, out);
    hipLaunchKernelGGL(k3b_loss, dim3(1), dim3(256), 0, stream, out);
    hipLaunchKernelGGL(k4_gather, dim3(N_TOK / 4 / 256, 8), dim3(256), 0, stream,
                       E, out);
  }
}